// Round 3
// baseline (430.364 us; speedup 1.0000x reference)
//
#include <hip/hip_runtime.h>

// MV_GCN on MI355X — round 3: occupancy attack.
// 1024-thread blocks (16 waves; 2 blocks/CU = 32 waves/CU = 8 waves/SIMD max)
// + 2-deep register prefetch of the L2/L3-streamed GEMM operand
// + fully-pipelined predicated edge pass.
// Math unchanged: dense 116x116 A_hat per (g,v) built once from edges;
// out = A_hat @ (X @ W) + b, channel-max -> feat[256,232] -> MLP.

#define NB 256
#define NODES 116
#define FEAT 115
#define LENN 6670
#define SEG2 13456
#define HID 128
#define HC 512
#define LSTR 120   // padded LDS row stride (480 B, 16B-aligned rows)

// ---------------- K1: H = X @ W_v per (g,v) tile ----------------
// 1024 thr: cg = t&63 -> 2 cols, rg = t>>6 (0..15) -> rows rg+16i, i<8
// (128 slots cover 116; clamped dups recompute/store identical values).
__global__ __launch_bounds__(1024, 8) void k_h_gemm(
    const float* __restrict__ x, const float* __restrict__ W1,
    const float* __restrict__ W2, float* __restrict__ Hws)
{
  __shared__ __align__(16) float sX[NODES * LSTR];
  const int bid = blockIdx.x;
  const int g = bid >> 1, v = bid & 1;
  const int tid = threadIdx.x;
  const float* __restrict__ W = v ? W2 : W1;
  const float* __restrict__ xg = x + (size_t)(g * 232 + v * 116) * FEAT;

  // zero (incl. pad cols) then fill — keeps K-loop uniform over k=0..115
  const float4 z4 = make_float4(0.f, 0.f, 0.f, 0.f);
  for (int i = tid; i < (NODES * LSTR) / 4; i += 1024) ((float4*)sX)[i] = z4;
  __syncthreads();
  for (int i = tid; i < NODES * FEAT; i += 1024) {
    int r = i / FEAT;          // magic mul
    int k = i - r * FEAT;
    sX[r * LSTR + k] = xg[i];  // coalesced global read
  }
  __syncthreads();

  const int cg = tid & 63, rg = tid >> 6;
  const int c0 = cg * 2;
  const float* __restrict__ Wc = W + c0;

  int rr[8];
#pragma unroll
  for (int i = 0; i < 8; ++i) {
    int r = rg + 16 * i;
    rr[i] = (r < NODES) ? r : (NODES - 1);
  }

  float2 acc[8];
#pragma unroll
  for (int i = 0; i < 8; ++i) acc[i] = make_float2(0.f, 0.f);

  // 2-deep prefetch of W chunks (4 rows x float2 each). kc=28 covers
  // k=112..115; W row 115 doesn't exist -> zero (X pad col 115 is zero too).
  float2 wbuf[2][4];
#pragma unroll
  for (int p = 0; p < 2; ++p) {
    const int k0 = 4 * p;
    wbuf[p][0] = *(const float2*)(Wc + (size_t)(k0 + 0) * HID);
    wbuf[p][1] = *(const float2*)(Wc + (size_t)(k0 + 1) * HID);
    wbuf[p][2] = *(const float2*)(Wc + (size_t)(k0 + 2) * HID);
    wbuf[p][3] = *(const float2*)(Wc + (size_t)(k0 + 3) * HID);
  }

  for (int kc = 0; kc < 29; ++kc) {
    float2 wc[4];
#pragma unroll
    for (int j = 0; j < 4; ++j) wc[j] = wbuf[kc & 1][j];
    if (kc + 2 <= 28) {
      const int kn = 4 * (kc + 2);
      float2* wb = wbuf[kc & 1];
      wb[0] = *(const float2*)(Wc + (size_t)(kn + 0) * HID);
      wb[1] = *(const float2*)(Wc + (size_t)(kn + 1) * HID);
      wb[2] = *(const float2*)(Wc + (size_t)(kn + 2) * HID);
      wb[3] = (kn + 3 < FEAT) ? *(const float2*)(Wc + (size_t)(kn + 3) * HID)
                              : make_float2(0.f, 0.f);
    }
    const int k0 = 4 * kc;
#pragma unroll
    for (int i = 0; i < 8; ++i) {
      float4 a = *(const float4*)&sX[rr[i] * LSTR + k0];  // wave-uniform bcast
      acc[i].x = fmaf(a.x, wc[0].x, acc[i].x);
      acc[i].x = fmaf(a.y, wc[1].x, acc[i].x);
      acc[i].x = fmaf(a.z, wc[2].x, acc[i].x);
      acc[i].x = fmaf(a.w, wc[3].x, acc[i].x);
      acc[i].y = fmaf(a.x, wc[0].y, acc[i].y);
      acc[i].y = fmaf(a.y, wc[1].y, acc[i].y);
      acc[i].y = fmaf(a.z, wc[2].y, acc[i].y);
      acc[i].y = fmaf(a.w, wc[3].y, acc[i].y);
    }
  }

  float* __restrict__ Ht = Hws + (size_t)bid * NODES * HID;
#pragma unroll
  for (int i = 0; i < 8; ++i)
    *(float2*)(Ht + (size_t)rr[i] * HID + c0) = acc[i];  // dup rows: same value
}

// ---------------- K2: build A_hat, out = A_hat @ H, channel-max ----------------
__global__ __launch_bounds__(1024, 8) void k_agg(
    const int* __restrict__ ei, const float* __restrict__ ew,
    const float* __restrict__ b1, const float* __restrict__ b2,
    const float* __restrict__ Hws, float* __restrict__ featws)
{
  __shared__ __align__(16) float sA[NODES * LSTR];
  __shared__ float dinv[NODES];
  const int bid = blockIdx.x;
  const int g = bid >> 1, v = bid & 1;
  const int tid = threadIdx.x;

  const float4 z4 = make_float4(0.f, 0.f, 0.f, 0.f);
  for (int i = tid; i < (NODES * LSTR) / 4; i += 1024) ((float4*)sA)[i] = z4;
  __syncthreads();

  // edge pass, fully pipelined: 7 predicated loads then 7 atomics.
  // OOB lanes use (0,0,0.0f): atomicAdd of 0 is numerically harmless.
  {
    const int eoff = g * SEG2 + v * LENN;
    const int nbase = g * 232 + v * 116;
    const int* __restrict__ srcp = ei + eoff;
    const int* __restrict__ dstp = ei + (size_t)NB * SEG2 + eoff;
    const float* __restrict__ wp = ew + eoff;
    int ss[7], dd[7];
    float ww[7];
#pragma unroll
    for (int j = 0; j < 7; ++j) {
      const int e = tid + j * 1024;
      const bool ok = (e < LENN);
      ss[j] = ok ? (srcp[e] - nbase) : 0;
      dd[j] = ok ? (dstp[e] - nbase) : 0;
      ww[j] = ok ? wp[e] : 0.f;
    }
#pragma unroll
    for (int j = 0; j < 7; ++j)
      atomicAdd(&sA[dd[j] * LSTR + ss[j]], ww[j]);
  }
  __syncthreads();

  // deg: 4 threads per row, stride-29 segments (breaks stride-120 aliasing)
  if (tid < 4 * NODES) {
    const int r = tid >> 2, q = tid & 3;
    const float* row = &sA[r * LSTR + q * 29];
    float s = 0.f;
#pragma unroll
    for (int j = 0; j < 29; ++j) s += row[j];
    s += __shfl_xor(s, 1, 64);
    s += __shfl_xor(s, 2, 64);
    if (q == 0) dinv[r] = rsqrtf(s + 1.0f);   // deg + 1 self-loop
  }
  __syncthreads();

  // normalize in place; fold self-loop dinv^2 into the diagonal
  for (int idx = tid; idx < NODES * NODES; idx += 1024) {
    int d = idx / NODES;
    int s = idx - d * NODES;
    float di = dinv[d];
    float val = sA[d * LSTR + s] * (di * dinv[s]);
    if (d == s) val += di * di;
    sA[d * LSTR + s] = val;
  }
  __syncthreads();

  // dense A_hat(LDS) @ H(global, 2-deep prefetch); 8x2 register tile
  const float* __restrict__ bv = v ? b2 : b1;
  const int cg = tid & 63, rg = tid >> 6;
  const int c0 = cg * 2;
  const float* __restrict__ Ht = Hws + (size_t)bid * NODES * HID + c0;

  int rr[8];
#pragma unroll
  for (int i = 0; i < 8; ++i) {
    int r = rg + 16 * i;
    rr[i] = (r < NODES) ? r : (NODES - 1);
  }

  float2 bb = *(const float2*)(bv + c0);
  float2 acc[8];
#pragma unroll
  for (int i = 0; i < 8; ++i) acc[i] = bb;

  float2 hbuf[2][4];
#pragma unroll
  for (int p = 0; p < 2; ++p) {
    const int s0 = 4 * p;
#pragma unroll
    for (int j = 0; j < 4; ++j)
      hbuf[p][j] = *(const float2*)(Ht + (size_t)(s0 + j) * HID);
  }

  for (int sc = 0; sc < 29; ++sc) {   // 116 = 29*4 exact, no tail
    float2 hc[4];
#pragma unroll
    for (int j = 0; j < 4; ++j) hc[j] = hbuf[sc & 1][j];
    if (sc + 2 <= 28) {
      const int sn = 4 * (sc + 2);
      float2* hb = hbuf[sc & 1];
#pragma unroll
      for (int j = 0; j < 4; ++j)
        hb[j] = *(const float2*)(Ht + (size_t)(sn + j) * HID);
    }
    const int s0 = 4 * sc;
#pragma unroll
    for (int i = 0; i < 8; ++i) {
      float4 a = *(const float4*)&sA[rr[i] * LSTR + s0];  // wave-uniform bcast
      acc[i].x = fmaf(a.x, hc[0].x, acc[i].x);
      acc[i].x = fmaf(a.y, hc[1].x, acc[i].x);
      acc[i].x = fmaf(a.z, hc[2].x, acc[i].x);
      acc[i].x = fmaf(a.w, hc[3].x, acc[i].x);
      acc[i].y = fmaf(a.x, hc[0].y, acc[i].y);
      acc[i].y = fmaf(a.y, hc[1].y, acc[i].y);
      acc[i].y = fmaf(a.z, hc[2].y, acc[i].y);
      acc[i].y = fmaf(a.w, hc[3].y, acc[i].y);
    }
  }

  // channel max across the wave (each lane holds 2 of the 128 channels)
#pragma unroll
  for (int i = 0; i < 8; ++i) {
    float m = fmaxf(acc[i].x, acc[i].y);
#pragma unroll
    for (int off = 32; off >= 1; off >>= 1)
      m = fmaxf(m, __shfl_xor(m, off, 64));
    if (cg == 0)
      featws[g * 232 + 2 * rr[i] + v] = m;  // stack([x1,x2],1) order; dups same
  }
}

// ---------------- K3: MLP  relu(feat@W6+b6)@W7+b7 ----------------
__global__ __launch_bounds__(512) void k_mlp(
    const float* __restrict__ featws, const float* __restrict__ W6,
    const float* __restrict__ b6, const float* __restrict__ W7,
    const float* __restrict__ b7, float* __restrict__ out)
{
  __shared__ float sf[232];
  __shared__ float red[8];
  const int g = blockIdx.x, tid = threadIdx.x;
  if (tid < 232) sf[tid] = featws[g * 232 + tid];
  __syncthreads();

  float a = b6[tid];
  const float* __restrict__ w6p = W6 + tid;
#pragma unroll 8
  for (int k = 0; k < 232; ++k)
    a = fmaf(sf[k], w6p[(size_t)k * HC], a);
  a = fmaxf(a, 0.f);
  float p = a * W7[tid];
#pragma unroll
  for (int off = 32; off >= 1; off >>= 1) p += __shfl_xor(p, off, 64);
  if ((tid & 63) == 0) red[tid >> 6] = p;
  __syncthreads();
  if (tid == 0) {
    float t = b7[0];
#pragma unroll
    for (int i = 0; i < 8; ++i) t += red[i];
    out[g] = t;
  }
}

extern "C" void kernel_launch(void* const* d_in, const int* in_sizes, int n_in,
                              void* d_out, int out_size, void* d_ws, size_t ws_size,
                              hipStream_t stream)
{
  const float* x  = (const float*)d_in[0];
  const int*   ei = (const int*)d_in[1];
  const float* ew = (const float*)d_in[2];
  // d_in[3] = batch (unused by reference)
  const float* W1 = (const float*)d_in[4];
  const float* b1 = (const float*)d_in[5];
  const float* W2 = (const float*)d_in[6];
  const float* b2 = (const float*)d_in[7];
  const float* W6 = (const float*)d_in[8];
  const float* b6 = (const float*)d_in[9];
  const float* W7 = (const float*)d_in[10];
  const float* b7 = (const float*)d_in[11];

  float* Hws    = (float*)d_ws;                       // 512*116*128 f32 = 30.4 MB
  float* featws = Hws + (size_t)512 * NODES * HID;    // 256*232 f32
  float* out    = (float*)d_out;

  hipLaunchKernelGGL(k_h_gemm, dim3(2 * NB), dim3(1024), 0, stream, x, W1, W2, Hws);
  hipLaunchKernelGGL(k_agg,    dim3(2 * NB), dim3(1024), 0, stream, ei, ew, b1, b2, Hws, featws);
  hipLaunchKernelGGL(k_mlp,    dim3(NB),     dim3(512),  0, stream, featws, W6, b6, W7, b7, out);
}

// Round 5
// 220.604 us; speedup vs baseline: 1.9508x; 1.9508x over previous
//
#include <hip/hip_runtime.h>

// MV_GCN on MI355X — round 5: fused kernel in REFERENCE association order.
// R4 failed numerics because (A@X)@W reassociates the 115-term X@W chains.
// Here: H = X@W computed first (bit-identical chain to the passing R2), kept
// in LDS; then A_hat built in X's LDS region; then out = A_hat@H all-LDS.
// LDS: sA 116x120 (55.7K, X then A_hat) + sH 116x128 (59.4K) + sW ping-pong
// (8K) + dinv = 120.8 KB -> 1 block/CU, 1024 thr = 4 waves/SIMD.
// __launch_bounds__(1024,4): VGPR cap 128 (NEVER cap 64 — R3 spill disaster).

#define NB 256
#define NODES 116
#define FEAT 115
#define LENN 6670
#define SEG2 13456
#define HID 128
#define HC 512
#define ASTR 120   // sA row stride (480 B, 16B-aligned rows)

__global__ __launch_bounds__(1024, 4) void k_fused(
    const float* __restrict__ x, const int* __restrict__ ei,
    const float* __restrict__ ew,
    const float* __restrict__ W1, const float* __restrict__ b1,
    const float* __restrict__ W2, const float* __restrict__ b2,
    float* __restrict__ featws)
{
  __shared__ __align__(16) float sA[NODES * ASTR];   // X (phase 1), A_hat (phase 2)
  __shared__ __align__(16) float sH[NODES * HID];    // H = X @ W
  __shared__ __align__(16) float sW[2][8 * HID];     // W chunk ping-pong (8 rows)
  __shared__ float dinv[NODES];

  const int bid = blockIdx.x;
  const int g = bid >> 1, v = bid & 1;
  const int tid = threadIdx.x;
  const float* __restrict__ W  = v ? W2 : W1;
  const float* __restrict__ bv = v ? b2 : b1;
  const float* __restrict__ xg = x + (size_t)(g * 232 + v * 116) * FEAT;

  // ---- stage X into sA (stride ASTR); pad cols [115,120) = 0 ----
  for (int i = tid; i < NODES * ASTR; i += 1024) {
    int r = i / ASTR;                 // const-divisor magic mul
    int k = i - r * ASTR;
    sA[i] = (k < FEAT) ? xg[r * FEAT + k] : 0.f;
  }
  // preload W chunk 0 element (1024 thr == 8 rows x 128 cols exactly)
  const int wrow = tid >> 7, wcol = tid & 127;
  float wr = (wrow < FEAT) ? W[(size_t)wrow * HID + wcol] : 0.f;
  __syncthreads();

  const int cg = tid & 63, rg = tid >> 6;   // rg in 0..15
  const int c0 = cg * 2;
  int rr[8];
#pragma unroll
  for (int i = 0; i < 8; ++i) {
    int r = rg + 16 * i;                    // 128 row slots cover 116 (clamp dup)
    rr[i] = (r < NODES) ? r : (NODES - 1);
  }

  // ================= phase 1: H = X @ W (reference association) =============
  // Per-channel fma chain: ascending k, 15 chunks of 8; k>=115 terms are
  // exact +0.0 (X pad cols and W pad rows both zeroed) -> bit-identical to R2.
  float2 acc[8];
#pragma unroll
  for (int i = 0; i < 8; ++i) acc[i] = make_float2(0.f, 0.f);

  for (int ch = 0; ch < 15; ++ch) {
    sW[ch & 1][tid] = wr;                   // publish this chunk
    if (ch < 14) {                          // prefetch next (in flight over barrier)
      const int k = 8 * (ch + 1) + wrow;
      wr = (k < FEAT) ? W[(size_t)k * HID + wcol] : 0.f;
    }
    __syncthreads();                        // chunk ready; prev-prev readers done

    const float* __restrict__ wb = sW[ch & 1];
    float2 wv[8];
#pragma unroll
    for (int j = 0; j < 8; ++j) wv[j] = *(const float2*)&wb[j * HID + c0];
    const int k0 = 8 * ch;
#pragma unroll
    for (int i = 0; i < 8; ++i) {
      const float* ap = &sA[rr[i] * ASTR + k0];
      float4 a0 = *(const float4*)ap;       // wave-uniform broadcast
      float4 a1 = *(const float4*)(ap + 4);
      acc[i].x = fmaf(a0.x, wv[0].x, acc[i].x);
      acc[i].y = fmaf(a0.x, wv[0].y, acc[i].y);
      acc[i].x = fmaf(a0.y, wv[1].x, acc[i].x);
      acc[i].y = fmaf(a0.y, wv[1].y, acc[i].y);
      acc[i].x = fmaf(a0.z, wv[2].x, acc[i].x);
      acc[i].y = fmaf(a0.z, wv[2].y, acc[i].y);
      acc[i].x = fmaf(a0.w, wv[3].x, acc[i].x);
      acc[i].y = fmaf(a0.w, wv[3].y, acc[i].y);
      acc[i].x = fmaf(a1.x, wv[4].x, acc[i].x);
      acc[i].y = fmaf(a1.x, wv[4].y, acc[i].y);
      acc[i].x = fmaf(a1.y, wv[5].x, acc[i].x);
      acc[i].y = fmaf(a1.y, wv[5].y, acc[i].y);
      acc[i].x = fmaf(a1.z, wv[6].x, acc[i].x);
      acc[i].y = fmaf(a1.z, wv[6].y, acc[i].y);
      acc[i].x = fmaf(a1.w, wv[7].x, acc[i].x);
      acc[i].y = fmaf(a1.w, wv[7].y, acc[i].y);
    }
  }

  // H -> LDS (region B); clamp-dup rows write identical bits (benign)
#pragma unroll
  for (int i = 0; i < 8; ++i)
    *(float2*)&sH[rr[i] * HID + c0] = acc[i];
  __syncthreads();                          // all phase-1 sA(X) reads done

  // ================= build A_hat in region A =================
  const float4 z4 = make_float4(0.f, 0.f, 0.f, 0.f);
  for (int i = tid; i < (NODES * ASTR) / 4; i += 1024) ((float4*)sA)[i] = z4;
  __syncthreads();

  {  // edge pass: A_raw[d][s] += w (pipelined predicated loads)
    const int eoff = g * SEG2 + v * LENN;
    const int nbase = g * 232 + v * 116;
    const int* __restrict__ srcp = ei + eoff;
    const int* __restrict__ dstp = ei + (size_t)NB * SEG2 + eoff;
    const float* __restrict__ wp = ew + eoff;
    int ss[7], dd[7];
    float ww[7];
#pragma unroll
    for (int j = 0; j < 7; ++j) {
      const int e = tid + j * 1024;
      const bool ok = (e < LENN);
      ss[j] = ok ? (srcp[e] - nbase) : 0;
      dd[j] = ok ? (dstp[e] - nbase) : 0;
      ww[j] = ok ? wp[e] : 0.f;
    }
#pragma unroll
    for (int j = 0; j < 7; ++j)
      atomicAdd(&sA[dd[j] * ASTR + ss[j]], ww[j]);
  }
  __syncthreads();

  // deg -> dinv (4 threads/row, stride-29 segments)
  if (tid < 4 * NODES) {
    const int r = tid >> 2, q = tid & 3;
    const float* row = &sA[r * ASTR + q * 29];
    float s = 0.f;
#pragma unroll
    for (int j = 0; j < 29; ++j) s += row[j];
    s += __shfl_xor(s, 1, 64);
    s += __shfl_xor(s, 2, 64);
    if (q == 0) dinv[r] = rsqrtf(s + 1.0f);  // deg + 1 self-loop
  }
  __syncthreads();

  // normalize in place; fold self-loop dinv^2 into the diagonal
  for (int idx = tid; idx < NODES * NODES; idx += 1024) {
    int d = idx / NODES;
    int s = idx - d * NODES;
    float di = dinv[d];
    float val = sA[d * ASTR + s] * (di * dinv[s]);
    if (d == s) val += di * di;
    sA[d * ASTR + s] = val;
  }
  __syncthreads();

  // ================= phase 2: out = A_hat @ H + b (all LDS, no barriers) ====
  float2 acc2[8];
  {
    float2 bb = *(const float2*)(bv + c0);
#pragma unroll
    for (int i = 0; i < 8; ++i) acc2[i] = bb;
  }

  for (int sc = 0; sc < 29; ++sc) {         // s = 0..115, 116 = 29*4 exact
    const int s0 = 4 * sc;
    float2 hv[4];
#pragma unroll
    for (int j = 0; j < 4; ++j) hv[j] = *(const float2*)&sH[(s0 + j) * HID + c0];
#pragma unroll
    for (int i = 0; i < 8; ++i) {
      float4 a = *(const float4*)&sA[rr[i] * ASTR + s0];  // wave-uniform bcast
      acc2[i].x = fmaf(a.x, hv[0].x, acc2[i].x);
      acc2[i].y = fmaf(a.x, hv[0].y, acc2[i].y);
      acc2[i].x = fmaf(a.y, hv[1].x, acc2[i].x);
      acc2[i].y = fmaf(a.y, hv[1].y, acc2[i].y);
      acc2[i].x = fmaf(a.z, hv[2].x, acc2[i].x);
      acc2[i].y = fmaf(a.z, hv[2].y, acc2[i].y);
      acc2[i].x = fmaf(a.w, hv[3].x, acc2[i].x);
      acc2[i].y = fmaf(a.w, hv[3].y, acc2[i].y);
    }
  }

  // ---- channel max over 128 cols (wave shfl), write feat ----
#pragma unroll
  for (int i = 0; i < 8; ++i) {
    float m = fmaxf(acc2[i].x, acc2[i].y);
#pragma unroll
    for (int off = 32; off >= 1; off >>= 1)
      m = fmaxf(m, __shfl_xor(m, off, 64));
    if (cg == 0)
      featws[g * 232 + 2 * rr[i] + v] = m;  // stack([x1,x2],1) order; dups same
  }
}

// ---------------- K3: MLP  relu(feat@W6+b6)@W7+b7 ----------------
__global__ __launch_bounds__(512) void k_mlp(
    const float* __restrict__ featws, const float* __restrict__ W6,
    const float* __restrict__ b6, const float* __restrict__ W7,
    const float* __restrict__ b7, float* __restrict__ out)
{
  __shared__ float sf[232];
  __shared__ float red[8];
  const int g = blockIdx.x, tid = threadIdx.x;
  if (tid < 232) sf[tid] = featws[g * 232 + tid];
  __syncthreads();

  float a = b6[tid];
  const float* __restrict__ w6p = W6 + tid;
#pragma unroll 8
  for (int k = 0; k < 232; ++k)
    a = fmaf(sf[k], w6p[(size_t)k * HC], a);
  a = fmaxf(a, 0.f);
  float p = a * W7[tid];
#pragma unroll
  for (int off = 32; off >= 1; off >>= 1) p += __shfl_xor(p, off, 64);
  if ((tid & 63) == 0) red[tid >> 6] = p;
  __syncthreads();
  if (tid == 0) {
    float t = b7[0];
#pragma unroll
    for (int i = 0; i < 8; ++i) t += red[i];
    out[g] = t;
  }
}

extern "C" void kernel_launch(void* const* d_in, const int* in_sizes, int n_in,
                              void* d_out, int out_size, void* d_ws, size_t ws_size,
                              hipStream_t stream)
{
  const float* x  = (const float*)d_in[0];
  const int*   ei = (const int*)d_in[1];
  const float* ew = (const float*)d_in[2];
  // d_in[3] = batch (unused by reference)
  const float* W1 = (const float*)d_in[4];
  const float* b1 = (const float*)d_in[5];
  const float* W2 = (const float*)d_in[6];
  const float* b2 = (const float*)d_in[7];
  const float* W6 = (const float*)d_in[8];
  const float* b6 = (const float*)d_in[9];
  const float* W7 = (const float*)d_in[10];
  const float* b7 = (const float*)d_in[11];

  float* featws = (float*)d_ws;          // 256*232 f32
  float* out    = (float*)d_out;

  hipLaunchKernelGGL(k_fused, dim3(2 * NB), dim3(1024), 0, stream,
                     x, ei, ew, W1, b1, W2, b2, featws);
  hipLaunchKernelGGL(k_mlp, dim3(NB), dim3(512), 0, stream,
                     featws, W6, b6, W7, b7, out);
}